// Round 4
// baseline (192.167 us; speedup 1.0000x reference)
//
#include <hip/hip_runtime.h>
#include <hip/hip_bf16.h>
#include <stdint.h>

#define IN_F 512
#define OUT_F 512
#define KDIM 512
#define BN 128          // per-block output columns (one nt slab)
#define BLK_ROWS 256    // per-block output rows (8 waves x 32)
#define NTHREADS 512

typedef __attribute__((ext_vector_type(8))) short short8;
typedef __attribute__((ext_vector_type(4))) float floatx4;

__device__ __forceinline__ ushort f2bf(float f) {
  uint32_t u = __builtin_bit_cast(uint32_t, f);
  uint32_t r = u + 0x7fffu + ((u >> 16) & 1u);   // RNE bf16
  return (ushort)(r >> 16);
}

typedef const __attribute__((address_space(1))) uint32_t* gas1_u32;
typedef __attribute__((address_space(3))) uint32_t* gas3_u32;

__device__ __forceinline__ void gload_lds16(const void* g, void* l) {
  // per-lane global src; LDS dest = wave-uniform base + lane*16 bytes
  __builtin_amdgcn_global_load_lds((gas1_u32)g, (gas3_u32)l, 16, 0, 0);
}

// ---------------------------------------------------------------------------
// Prep: W_eff (512x512) bf16, stored as 4 slabs [nt][128][512] in the exact
// (XOR-swizzled) LDS image the GEMM stages linearly via global_load_lds.
// ---------------------------------------------------------------------------
__global__ void quat_prep_kernel(const float* __restrict__ wr, const float* __restrict__ wi,
                                 const float* __restrict__ wj, const float* __restrict__ wk,
                                 ushort* __restrict__ Bimg) {
  int idx = blockIdx.x * 256 + threadIdx.x;
  if (idx >= 512 * 512) return;
  int n = idx >> 9;        // output-feature index O
  int k = idx & 511;       // input-feature index C
  int og = n >> 7, o = n & 127, cg = k >> 7, c = k & 127;
  static const int   blkT[16] = {0,1,2,3, 1,0,3,2, 2,3,0,1, 3,2,1,0};
  static const float sgnT[16] = {1.f,-1.f,-1.f,-1.f, 1.f,1.f,1.f,-1.f,
                                 1.f,-1.f,1.f,1.f,   1.f,1.f,-1.f,1.f};
  int sel = og * 4 + cg;
  const float* Ws;
  switch (blkT[sel]) {
    case 0: Ws = wr; break;
    case 1: Ws = wi; break;
    case 2: Ws = wj; break;
    default: Ws = wk; break;
  }
  float v = sgnT[sel] * Ws[o * 128 + c];
  int nt = n >> 7, nl = n & 127;
  int dst = nt * (BN * KDIM) + nl * KDIM + (k ^ ((nl & 7) << 3));
  Bimg[dst] = f2bf(v);
}

// ---------------------------------------------------------------------------
// GEMM: out[M,512] = X[M,512] * W_eff^T (+bias)
// Whole B slab (128x512 bf16 = 128KB) resident in LDS; ONE barrier total.
// 8 free-running waves, each owns a 32x128 tile, streams A from global with
// double-buffered register chunks (BK=64). No K-loop barriers.
// ---------------------------------------------------------------------------
__global__ void __launch_bounds__(NTHREADS, 2)
quat_gemm_kernel(const float* __restrict__ X, const ushort* __restrict__ Bimg,
                 const float* __restrict__ bias, float* __restrict__ Out) {
  __shared__ __align__(16) ushort Bb[BN * KDIM];   // 128 KB

  int nwg = gridDim.x;
  int bid = blockIdx.x;
  int wgid = bid;
  if ((nwg & 7) == 0) {                 // bijective XCD swizzle
    int per = nwg >> 3;
    wgid = (bid & 7) * per + (bid >> 3);
  }
  int mt = wgid >> 2;                   // 4 nt-siblings adjacent -> same XCD L2
  int nt = wgid & 3;

  int tid = threadIdx.x, lane = tid & 63, wid = tid >> 6;
  const int lrow = lane & 15;
  const int lg   = lane >> 4;

  // ---- stage B slab once: 128KB linear copy, pre-swizzled at prep time ----
  // Units: 1 gload_lds16 = 64 lanes x 16B = 1024B = 512 ushorts.
  // Per wave: 16 chunks x 512 = 8192 ushorts (16KB); 8 waves cover 128KB.
  {
    const ushort* src = Bimg + nt * (BN * KDIM) + wid * 8192 + lane * 8;
    ushort* dst = Bb + wid * 8192;
#pragma unroll
    for (int i = 0; i < 16; ++i)
      gload_lds16(src + i * 512, dst + i * 512);
  }
  __syncthreads();                      // the only barrier

  // ---- per-wave streaming K-loop ----
  const float* Ar0 = X + ((size_t)(mt * BLK_ROWS + wid * 32 + lrow)) * KDIM + lg * 8;
  const float* Ar1 = Ar0 + (size_t)16 * KDIM;

  floatx4 acc[2][8];
#pragma unroll
  for (int m = 0; m < 2; ++m)
#pragma unroll
    for (int n = 0; n < 8; ++n) acc[m][n] = {0.f, 0.f, 0.f, 0.f};

  float4 av[2][8];                      // double-buffered A chunk (BK=64)

  auto issueA = [&](int kt, float4 (&buf)[8]) {
    const float* p0 = Ar0 + kt * 64;
    const float* p1 = Ar1 + kt * 64;
    buf[0] = *reinterpret_cast<const float4*>(p0);
    buf[1] = *reinterpret_cast<const float4*>(p0 + 4);
    buf[2] = *reinterpret_cast<const float4*>(p0 + 32);
    buf[3] = *reinterpret_cast<const float4*>(p0 + 36);
    buf[4] = *reinterpret_cast<const float4*>(p1);
    buf[5] = *reinterpret_cast<const float4*>(p1 + 4);
    buf[6] = *reinterpret_cast<const float4*>(p1 + 32);
    buf[7] = *reinterpret_cast<const float4*>(p1 + 36);
  };

  auto cvt8 = [&](float4 x, float4 y) -> short8 {
    short8 r;
    r[0] = (short)f2bf(x.x); r[1] = (short)f2bf(x.y);
    r[2] = (short)f2bf(x.z); r[3] = (short)f2bf(x.w);
    r[4] = (short)f2bf(y.x); r[5] = (short)f2bf(y.y);
    r[6] = (short)f2bf(y.z); r[7] = (short)f2bf(y.w);
    return r;
  };

  issueA(0, av[0]);

#pragma unroll
  for (int kt = 0; kt < 8; ++kt) {
    float4 (&cur)[8] = av[kt & 1];
    float4 (&nxt)[8] = av[(kt + 1) & 1];
    if (kt < 7) issueA(kt + 1, nxt);    // in flight across whole chunk compute

    short8 af00 = cvt8(cur[0], cur[1]); // m0, k[0:32)
    short8 af01 = cvt8(cur[2], cur[3]); // m0, k[32:64)
    short8 af10 = cvt8(cur[4], cur[5]); // m1, k[0:32)
    short8 af11 = cvt8(cur[6], cur[7]); // m1, k[32:64)

    const int kb = kt * 64 + lg * 8;
#pragma unroll
    for (int n = 0; n < 8; ++n) {
      int row = n * 16 + lrow;
      int sw = (row & 7) << 3;
      short8 b0 = *reinterpret_cast<const short8*>(Bb + row * KDIM + (kb ^ sw));
      short8 b1 = *reinterpret_cast<const short8*>(Bb + row * KDIM + ((kb + 32) ^ sw));
      acc[0][n] = __builtin_amdgcn_mfma_f32_16x16x32_bf16(af00, b0, acc[0][n], 0, 0, 0);
      acc[1][n] = __builtin_amdgcn_mfma_f32_16x16x32_bf16(af10, b0, acc[1][n], 0, 0, 0);
      acc[0][n] = __builtin_amdgcn_mfma_f32_16x16x32_bf16(af01, b1, acc[0][n], 0, 0, 0);
      acc[1][n] = __builtin_amdgcn_mfma_f32_16x16x32_bf16(af11, b1, acc[1][n], 0, 0, 0);
    }
  }

  // ---- epilogue ----
  float* Ob = Out + (size_t)(mt * BLK_ROWS + wid * 32) * OUT_F + nt * BN;
  const float* bb = bias + nt * BN;
#pragma unroll
  for (int n = 0; n < 8; ++n) {
    int col = n * 16 + lrow;
    float bv = bb[col];
#pragma unroll
    for (int m = 0; m < 2; ++m) {
      int r0 = m * 16 + lg * 4;
#pragma unroll
      for (int j = 0; j < 4; ++j)
        Ob[(size_t)(r0 + j) * OUT_F + col] = acc[m][n][j] + bv;
    }
  }
}

extern "C" void kernel_launch(void* const* d_in, const int* in_sizes, int n_in,
                              void* d_out, int out_size, void* d_ws, size_t ws_size,
                              hipStream_t stream) {
  const float* x    = (const float*)d_in[0];
  const float* wr   = (const float*)d_in[1];
  const float* wi   = (const float*)d_in[2];
  const float* wj   = (const float*)d_in[3];
  const float* wk   = (const float*)d_in[4];
  const float* bias = (const float*)d_in[5];
  float* out = (float*)d_out;
  ushort* Bimg = (ushort*)d_ws;         // 512 KB

  int M = in_sizes[0] / IN_F;           // 131072
  int nwg = (M / BLK_ROWS) * (OUT_F / BN);   // 512 * 4 = 2048

  hipLaunchKernelGGL(quat_prep_kernel, dim3((512 * 512 + 255) / 256), dim3(256), 0, stream,
                     wr, wi, wj, wk, Bimg);
  hipLaunchKernelGGL(quat_gemm_kernel, dim3(nwg), dim3(NTHREADS), 0, stream,
                     x, Bimg, bias, out);
}